// Round 5
// baseline (376.676 us; speedup 1.0000x reference)
//
#include <hip/hip_runtime.h>

// GCN 2-layer. R5: 5-dispatch pipeline.
//  k_sort  : bucket sort by dst>>7 (atomic reservation, fixed-stride regions)
//  k_sort2 : per-bucket LDS counting sort by src-chunk (src>>12) IN-PLACE,
//            fused with deg (dstLow hist) -> dinv/u. Emits chunk run offsets.
//  k_agg1  : per bucket, loop chunks: stage u-chunk in LDS (coalesced),
//            per-edge LDS read + wave-private LDS atomic; fused MLP -> w.
//  k_agg2  : same with float2 w-chunks; fused log_softmax + mean reduce.
// packed word: bits[16:0]=src, bits[23:17]=dst&127.

#define TPB 256
#define SORT_BLK 256
#define BSHIFT 7
#define BNODES 128
#define MAXBUCK 1024
#define BSTRIDE 6144      // words per bucket region; mean 4092, sigma ~64
#define CSHIFT 12
#define CSZ 4096          // src-chunk size (u-slice 16 KB)
#define MAXCHUNK 32

// ---------------- bucket sort (count+place fused, atomic reservation) --------

__global__ __launch_bounds__(TPB) void k_sort(const int* __restrict__ ei, int E, int epb,
                                              int nbuck, int* __restrict__ gcur,
                                              unsigned* __restrict__ packed) {
    __shared__ int h[MAXBUCK];
    for (int b = threadIdx.x; b < nbuck; b += TPB) h[b] = 0;
    __syncthreads();
    const int4* d4 = (const int4*)(ei + E);
    int nq = epb >> 2;
    int q0 = blockIdx.x * nq;
    for (int j = threadIdx.x; j < nq; j += TPB) {
        int q = q0 + j;
        int e = q << 2;
        if (e + 3 < E) {
            int4 v = d4[q];
            atomicAdd(&h[v.x >> BSHIFT], 1);
            atomicAdd(&h[v.y >> BSHIFT], 1);
            atomicAdd(&h[v.z >> BSHIFT], 1);
            atomicAdd(&h[v.w >> BSHIFT], 1);
        } else {
            for (int k = 0; k < 4; ++k)
                if (e + k < E) atomicAdd(&h[(ei + E)[e + k] >> BSHIFT], 1);
        }
    }
    __syncthreads();
    for (int b = threadIdx.x; b < nbuck; b += TPB) {
        int c = h[b];
        h[b] = c ? atomicAdd(&gcur[b], c) : 0;
    }
    __syncthreads();
    const int4* s4 = (const int4*)ei;
    for (int j = threadIdx.x; j < nq; j += TPB) {
        int q = q0 + j;
        int e = q << 2;
        if (e + 3 < E) {
            int4 vs = s4[q];
            int4 vd = d4[q];
            int b, p;
            b = vd.x >> BSHIFT; p = atomicAdd(&h[b], 1);
            packed[b * BSTRIDE + p] = ((unsigned)(vd.x & (BNODES - 1)) << 17) | (unsigned)vs.x;
            b = vd.y >> BSHIFT; p = atomicAdd(&h[b], 1);
            packed[b * BSTRIDE + p] = ((unsigned)(vd.y & (BNODES - 1)) << 17) | (unsigned)vs.y;
            b = vd.z >> BSHIFT; p = atomicAdd(&h[b], 1);
            packed[b * BSTRIDE + p] = ((unsigned)(vd.z & (BNODES - 1)) << 17) | (unsigned)vs.z;
            b = vd.w >> BSHIFT; p = atomicAdd(&h[b], 1);
            packed[b * BSTRIDE + p] = ((unsigned)(vd.w & (BNODES - 1)) << 17) | (unsigned)vs.w;
        } else {
            for (int k = 0; k < 4; ++k) {
                int ee = e + k;
                if (ee < E) {
                    int s = ei[ee], d = ei[E + ee];
                    int b = d >> BSHIFT;
                    int p = atomicAdd(&h[b], 1);
                    packed[b * BSTRIDE + p] = ((unsigned)(d & (BNODES - 1)) << 17) | (unsigned)s;
                }
            }
        }
    }
}

// ------- per-bucket chunk sort (in place) + deg/dinv/u + chunk offsets -------

__global__ __launch_bounds__(TPB) void k_sort2(unsigned* __restrict__ packed,
                                               const int* __restrict__ gcur,
                                               const float* __restrict__ x,
                                               float* __restrict__ dinv,
                                               float* __restrict__ u,
                                               int* __restrict__ chunkOff,
                                               int nchunk, int N) {
    __shared__ unsigned wbuf[BSTRIDE];
    __shared__ int cntc[4][MAXCHUNK];
    __shared__ int cntd[4][BNODES];
    __shared__ int scanA[MAXCHUNK + 1];
    __shared__ int cur[MAXCHUNK];
    int wv = threadIdx.x >> 6;
    for (int k = threadIdx.x; k < 4 * MAXCHUNK; k += TPB) ((int*)cntc)[k] = 0;
    for (int k = threadIdx.x; k < 4 * BNODES; k += TPB) ((int*)cntd)[k] = 0;
    __syncthreads();
    int b = blockIdx.x;
    int sz = gcur[b];
    unsigned* gbase = packed + (size_t)b * BSTRIDE;
    // load to LDS + both histograms
    for (int j = threadIdx.x; j < sz; j += TPB) {
        unsigned wd = gbase[j];
        wbuf[j] = wd;
        atomicAdd(&cntc[wv][(wd & 0x1FFFF) >> CSHIFT], 1);
        atomicAdd(&cntd[wv][(wd >> 17) & 127], 1);
    }
    __syncthreads();
    // dinv/u for this bucket's nodes (deg = dstLow hist)
    if (threadIdx.x < BNODES) {
        int t = threadIdx.x;
        int node = (b << BSHIFT) + t;
        if (node < N) {
            int deg = cntd[0][t] + cntd[1][t] + cntd[2][t] + cntd[3][t];
            float di = rsqrtf((float)(deg + 1));   // +1 self-loop
            dinv[node] = di;
            u[node] = di * x[node];
        }
    }
    // exclusive scan of chunk histogram (thread 0; 25 bins)
    if (threadIdx.x == 0) {
        int run = 0;
        for (int c = 0; c < nchunk; ++c) {
            int v = cntc[0][c] + cntc[1][c] + cntc[2][c] + cntc[3][c];
            scanA[c] = run;
            run += v;
        }
        scanA[nchunk] = run;   // == sz
    }
    __syncthreads();
    if (threadIdx.x <= nchunk)
        chunkOff[b * (MAXCHUNK + 1) + threadIdx.x] = scanA[threadIdx.x];
    if (threadIdx.x < nchunk) cur[threadIdx.x] = scanA[threadIdx.x];
    __syncthreads();
    // scatter back to global in chunk-grouped order (in place; source is LDS)
    for (int j = threadIdx.x; j < sz; j += TPB) {
        unsigned wd = wbuf[j];
        int c = (wd & 0x1FFFF) >> CSHIFT;
        int p = atomicAdd(&cur[c], 1);
        gbase[p] = wd;
    }
}

// ---------------- layer-1 aggregation + MLP (per bucket) ----------------

__global__ __launch_bounds__(TPB) void k_agg1(const unsigned* __restrict__ packed,
                                              const int* __restrict__ chunkOff,
                                              const float* __restrict__ dinv,
                                              const float* __restrict__ u,
                                              const float* __restrict__ W1,
                                              const float* __restrict__ b1,
                                              const float* __restrict__ W2,
                                              float2* __restrict__ w,
                                              int nchunk, int N) {
    __shared__ float uStage[CSZ];
    __shared__ float acc[4][BNODES];
    __shared__ float sW1[64], sb1[64], sW2[128];
    if (threadIdx.x < 64) { sW1[threadIdx.x] = W1[threadIdx.x]; sb1[threadIdx.x] = b1[threadIdx.x]; }
    if (threadIdx.x < 128) sW2[threadIdx.x] = W2[threadIdx.x];
    for (int k = threadIdx.x; k < 4 * BNODES; k += TPB) ((float*)acc)[k] = 0.f;
    __syncthreads();
    int b = blockIdx.x;
    const unsigned* gbase = packed + (size_t)b * BSTRIDE;
    const int* off = chunkOff + b * (MAXCHUNK + 1);
    int wv = threadIdx.x >> 6;
    for (int c = 0; c < nchunk; ++c) {
        int o0 = off[c], o1 = off[c + 1];
        if (o0 == o1) continue;
        int gb = c << CSHIFT;
        #pragma unroll
        for (int k = 0; k < CSZ / TPB; ++k) {
            int idx = gb + threadIdx.x + k * TPB;
            uStage[threadIdx.x + k * TPB] = (idx < N) ? u[idx] : 0.f;
        }
        __syncthreads();
        for (int j = o0 + threadIdx.x; j < o1; j += TPB) {
            unsigned wd = gbase[j];
            float v = uStage[wd & (CSZ - 1)];
            atomicAdd(&acc[wv][(wd >> 17) & 127], v);
        }
        __syncthreads();
    }
    if (threadIdx.x < BNODES) {
        int t = threadIdx.x;
        int node = (b << BSHIFT) + t;
        if (node < N) {
            float di = dinv[node];
            float sv = di * (acc[0][t] + acc[1][t] + acc[2][t] + acc[3][t] + u[node]);
            float z0 = 0.f, z1 = 0.f;
            #pragma unroll
            for (int j = 0; j < 64; ++j) {
                float h = fmaxf(fmaf(sv, sW1[j], sb1[j]), 0.f);
                z0 = fmaf(h, sW2[2 * j], z0);
                z1 = fmaf(h, sW2[2 * j + 1], z1);
            }
            w[node] = make_float2(di * z0, di * z1);  // pre-scaled by dinv[src]
        }
    }
}

// ---------------- layer-2 aggregation + log_softmax + mean ----------------

__global__ __launch_bounds__(TPB) void k_agg2(const unsigned* __restrict__ packed,
                                              const int* __restrict__ chunkOff,
                                              const float* __restrict__ dinv,
                                              const float2* __restrict__ w,
                                              const float* __restrict__ b2,
                                              float* __restrict__ accum,
                                              int nchunk, int N) {
    __shared__ float2 wStage[CSZ];
    __shared__ float accx[4][BNODES], accy[4][BNODES];
    for (int k = threadIdx.x; k < 4 * BNODES; k += TPB) {
        ((float*)accx)[k] = 0.f;
        ((float*)accy)[k] = 0.f;
    }
    __syncthreads();
    int b = blockIdx.x;
    const unsigned* gbase = packed + (size_t)b * BSTRIDE;
    const int* off = chunkOff + b * (MAXCHUNK + 1);
    int wv = threadIdx.x >> 6;
    for (int c = 0; c < nchunk; ++c) {
        int o0 = off[c], o1 = off[c + 1];
        if (o0 == o1) continue;
        int gb = c << CSHIFT;
        #pragma unroll
        for (int k = 0; k < CSZ / TPB; ++k) {
            int idx = gb + threadIdx.x + k * TPB;
            wStage[threadIdx.x + k * TPB] = (idx < N) ? w[idx] : make_float2(0.f, 0.f);
        }
        __syncthreads();
        for (int j = o0 + threadIdx.x; j < o1; j += TPB) {
            unsigned wd = gbase[j];
            float2 v = wStage[wd & (CSZ - 1)];
            int l = (wd >> 17) & 127;
            atomicAdd(&accx[wv][l], v.x);
            atomicAdd(&accy[wv][l], v.y);
        }
        __syncthreads();
    }
    float l0 = 0.f, l1 = 0.f;
    if (threadIdx.x < BNODES) {
        int t = threadIdx.x;
        int node = (b << BSHIFT) + t;
        if (node < N) {
            float di = dinv[node];
            float2 wi = w[node];
            float a0 = di * (accx[0][t] + accx[1][t] + accx[2][t] + accx[3][t] + wi.x) + b2[0];
            float a1 = di * (accy[0][t] + accy[1][t] + accy[2][t] + accy[3][t] + wi.y) + b2[1];
            float m = fmaxf(a0, a1);
            float lse = m + logf(expf(a0 - m) + expf(a1 - m));
            l0 = a0 - lse;
            l1 = a1 - lse;
        }
    }
    #pragma unroll
    for (int off2 = 32; off2 > 0; off2 >>= 1) {
        l0 += __shfl_down(l0, off2, 64);
        l1 += __shfl_down(l1, off2, 64);
    }
    __shared__ float s0[TPB / 64], s1[TPB / 64];
    int wid = threadIdx.x >> 6, lane = threadIdx.x & 63;
    if (lane == 0) { s0[wid] = l0; s1[wid] = l1; }
    __syncthreads();
    if (threadIdx.x == 0) {
        float t0 = 0.f, t1 = 0.f;
        #pragma unroll
        for (int k = 0; k < TPB / 64; ++k) { t0 += s0[k]; t1 += s1[k]; }
        atomicAdd(&accum[0], t0);
        atomicAdd(&accum[1], t1);
    }
}

__global__ void k_finalize(const float* __restrict__ accum, float* __restrict__ out, float invN) {
    out[0] = accum[0] * invN;
    out[1] = accum[1] * invN;
}

// ---------------- fallback (global-atomic path) ----------------

__global__ void k_hist(const int* __restrict__ dst, int E, int* __restrict__ deg) {
    int e = blockIdx.x * TPB + threadIdx.x;
    if (e < E) atomicAdd(&deg[dst[e]], 1);
}
__global__ void k_dinv_u(const int* __restrict__ deg, const float* __restrict__ x,
                         float* __restrict__ dinv, float* __restrict__ u, int N) {
    int i = blockIdx.x * TPB + threadIdx.x;
    if (i < N) {
        float di = rsqrtf((float)(deg[i] + 1));
        dinv[i] = di;
        u[i] = di * x[i];
    }
}
__global__ void k_scatter1(const int* __restrict__ ei, int E,
                           const float* __restrict__ u, float* __restrict__ t) {
    int e = blockIdx.x * TPB + threadIdx.x;
    if (e < E) atomicAdd(&t[ei[E + e]], u[ei[e]]);
}
__global__ void k_node_mid_fb(const float* __restrict__ dinv, const float* __restrict__ u,
                              const float* __restrict__ t,
                              const float* __restrict__ W1, const float* __restrict__ b1,
                              const float* __restrict__ W2, float2* __restrict__ w, int N) {
    __shared__ float sW1[64], sb1[64], sW2[128];
    if (threadIdx.x < 64) { sW1[threadIdx.x] = W1[threadIdx.x]; sb1[threadIdx.x] = b1[threadIdx.x]; }
    if (threadIdx.x < 128) sW2[threadIdx.x] = W2[threadIdx.x];
    __syncthreads();
    int i = blockIdx.x * TPB + threadIdx.x;
    if (i < N) {
        float di = dinv[i];
        float s = di * (t[i] + u[i]);
        float z0 = 0.f, z1 = 0.f;
        #pragma unroll
        for (int j = 0; j < 64; ++j) {
            float h = fmaxf(fmaf(s, sW1[j], sb1[j]), 0.f);
            z0 = fmaf(h, sW2[2 * j], z0);
            z1 = fmaf(h, sW2[2 * j + 1], z1);
        }
        w[i] = make_float2(di * z0, di * z1);
    }
}
__global__ void k_scatter2(const int* __restrict__ ei, int E,
                           const float2* __restrict__ w, float* __restrict__ acc) {
    int e = blockIdx.x * TPB + threadIdx.x;
    if (e < E) {
        float2 ws = w[ei[e]];
        int d = ei[E + e];
        atomicAdd(&acc[2 * d], ws.x);
        atomicAdd(&acc[2 * d + 1], ws.y);
    }
}
__global__ void k_node_out_fb(const float* __restrict__ dinv, const float2* __restrict__ w,
                              const float2* __restrict__ acc, const float* __restrict__ b2,
                              float* __restrict__ accum, int N) {
    int i = blockIdx.x * TPB + threadIdx.x;
    float l0 = 0.f, l1 = 0.f;
    if (i < N) {
        float di = dinv[i];
        float2 a = acc[i];
        float2 ww = w[i];
        float a0 = di * (a.x + ww.x) + b2[0];
        float a1 = di * (a.y + ww.y) + b2[1];
        float m = fmaxf(a0, a1);
        float lse = m + logf(expf(a0 - m) + expf(a1 - m));
        l0 = a0 - lse;
        l1 = a1 - lse;
    }
    #pragma unroll
    for (int off = 32; off > 0; off >>= 1) {
        l0 += __shfl_down(l0, off, 64);
        l1 += __shfl_down(l1, off, 64);
    }
    __shared__ float s0[TPB / 64], s1[TPB / 64];
    int wid = threadIdx.x >> 6, lane = threadIdx.x & 63;
    if (lane == 0) { s0[wid] = l0; s1[wid] = l1; }
    __syncthreads();
    if (threadIdx.x == 0) {
        float t0 = 0.f, t1 = 0.f;
        #pragma unroll
        for (int k = 0; k < TPB / 64; ++k) { t0 += s0[k]; t1 += s1[k]; }
        atomicAdd(&accum[0], t0);
        atomicAdd(&accum[1], t1);
    }
}

extern "C" void kernel_launch(void* const* d_in, const int* in_sizes, int n_in,
                              void* d_out, int out_size, void* d_ws, size_t ws_size,
                              hipStream_t stream) {
    const float* x  = (const float*)d_in[0];
    const int*   ei = (const int*)d_in[1];
    const float* W1 = (const float*)d_in[2];
    const float* b1 = (const float*)d_in[3];
    const float* W2 = (const float*)d_in[4];
    const float* b2 = (const float*)d_in[5];
    float* out = (float*)d_out;

    const int N = in_sizes[0];
    const int E = in_sizes[1] / 2;
    const int nbuck = (N + BNODES - 1) >> BSHIFT;
    const int nchunk = (N + CSZ - 1) >> CSHIFT;
    const int gridN = (N + TPB - 1) / TPB;
    const int gridE = (E + TPB - 1) / TPB;

    size_t offPacked = 0;
    size_t offW      = offPacked + (size_t)nbuck * BSTRIDE * 4;
    size_t offDinv   = offW + (size_t)N * 8;
    size_t offU      = offDinv + (size_t)N * 4;
    size_t offGcur   = offU + (size_t)N * 4;
    size_t offAccum  = offGcur + (size_t)nbuck * 4;
    size_t offCOff   = offAccum + 8;
    size_t need      = offCOff + (size_t)nbuck * (MAXCHUNK + 1) * 4;

    if (ws_size >= need && nbuck <= MAXBUCK && N <= (1 << 17) && nchunk <= MAXCHUNK) {
        unsigned* packed   = (unsigned*)((char*)d_ws + offPacked);
        float2*   w        = (float2*)((char*)d_ws + offW);
        float*    dinv     = (float*)((char*)d_ws + offDinv);
        float*    u        = (float*)((char*)d_ws + offU);
        int*      gcur     = (int*)((char*)d_ws + offGcur);
        float*    accum    = (float*)((char*)d_ws + offAccum);
        int*      chunkOff = (int*)((char*)d_ws + offCOff);

        hipMemsetAsync(gcur, 0, (size_t)nbuck * 4 + 8, stream);

        int epb = (((E + SORT_BLK - 1) / SORT_BLK) + 3) & ~3;

        k_sort<<<SORT_BLK, TPB, 0, stream>>>(ei, E, epb, nbuck, gcur, packed);
        k_sort2<<<nbuck, TPB, 0, stream>>>(packed, gcur, x, dinv, u, chunkOff, nchunk, N);
        k_agg1<<<nbuck, TPB, 0, stream>>>(packed, chunkOff, dinv, u, W1, b1, W2, w, nchunk, N);
        k_agg2<<<nbuck, TPB, 0, stream>>>(packed, chunkOff, dinv, (const float2*)w, b2, accum, nchunk, N);
        k_finalize<<<1, 64, 0, stream>>>(accum, out, 1.0f / (float)N);
    } else {
        int*   deg   = (int*)d_ws;
        float* t     = (float*)(deg + N);
        float* acc   = t + N;
        float* accum = acc + 2 * N;
        float* dinv  = accum + 2;
        float* u     = dinv + N;
        float2* w    = (float2*)(u + N);
        hipMemsetAsync(d_ws, 0, (size_t)(4 * N + 2) * sizeof(float), stream);
        k_hist<<<gridE, TPB, 0, stream>>>(ei + E, E, deg);
        k_dinv_u<<<gridN, TPB, 0, stream>>>(deg, x, dinv, u, N);
        k_scatter1<<<gridE, TPB, 0, stream>>>(ei, E, u, t);
        k_node_mid_fb<<<gridN, TPB, 0, stream>>>(dinv, u, t, W1, b1, W2, w, N);
        k_scatter2<<<gridE, TPB, 0, stream>>>(ei, E, w, acc);
        k_node_out_fb<<<gridN, TPB, 0, stream>>>(dinv, w, (const float2*)acc, b2, accum, N);
        k_finalize<<<1, 64, 0, stream>>>(accum, out, 1.0f / (float)N);
    }
}

// Round 6
// 185.449 us; speedup vs baseline: 2.0312x; 2.0312x over previous
//
#include <hip/hip_runtime.h>

// GCN 2-layer. R6 = R4 pipeline (5 dispatches) with wider kernels:
//  k_sort  : bucket sort by dst>>7 (atomic reservation, fixed-stride regions), TPB=512
//  k_deg_u : per-bucket deg hist -> dinv/u, TPB=512, 8 wave-private copies
//  k_agg1  : per-bucket layer-1 scalar aggregate (per-edge L2 gathers, 8-edge
//            batch, 8 wave-private LDS copies) + fused 64-wide MLP -> w
//  k_agg2  : same for float2 + fused log_softmax + mean reduction
// packed word: bits[16:0]=src, bits[23:17]=dst&127.
// R5 lesson: do NOT stage u/w chunks in LDS -- per-chunk edge density (~164
// edges per 16KB chunk) makes staging a 25x traffic loss + 50 barriers/bucket.

#define TPB 512
#define SORT_BLK 256
#define BSHIFT 7
#define BNODES 128
#define MAXBUCK 1024
#define BSTRIDE 6144      // words per bucket region; mean 4092, sigma ~64 -> 32 sigma

// ---------------- bucket sort (count+place fused, atomic reservation) --------

__global__ __launch_bounds__(TPB) void k_sort(const int* __restrict__ ei, int E, int epb,
                                              int nbuck, int* __restrict__ gcur,
                                              unsigned* __restrict__ packed) {
    __shared__ int h[MAXBUCK];
    for (int b = threadIdx.x; b < nbuck; b += TPB) h[b] = 0;
    __syncthreads();
    const int4* d4 = (const int4*)(ei + E);
    int nq = epb >> 2;
    int q0 = blockIdx.x * nq;
    for (int j = threadIdx.x; j < nq; j += TPB) {
        int q = q0 + j;
        int e = q << 2;
        if (e + 3 < E) {
            int4 v = d4[q];
            atomicAdd(&h[v.x >> BSHIFT], 1);
            atomicAdd(&h[v.y >> BSHIFT], 1);
            atomicAdd(&h[v.z >> BSHIFT], 1);
            atomicAdd(&h[v.w >> BSHIFT], 1);
        } else {
            for (int k = 0; k < 4; ++k)
                if (e + k < E) atomicAdd(&h[(ei + E)[e + k] >> BSHIFT], 1);
        }
    }
    __syncthreads();
    for (int b = threadIdx.x; b < nbuck; b += TPB) {
        int c = h[b];
        h[b] = c ? atomicAdd(&gcur[b], c) : 0;
    }
    __syncthreads();
    const int4* s4 = (const int4*)ei;
    for (int j = threadIdx.x; j < nq; j += TPB) {
        int q = q0 + j;
        int e = q << 2;
        if (e + 3 < E) {
            int4 vs = s4[q];
            int4 vd = d4[q];
            int b, p;
            b = vd.x >> BSHIFT; p = atomicAdd(&h[b], 1);
            packed[b * BSTRIDE + p] = ((unsigned)(vd.x & (BNODES - 1)) << 17) | (unsigned)vs.x;
            b = vd.y >> BSHIFT; p = atomicAdd(&h[b], 1);
            packed[b * BSTRIDE + p] = ((unsigned)(vd.y & (BNODES - 1)) << 17) | (unsigned)vs.y;
            b = vd.z >> BSHIFT; p = atomicAdd(&h[b], 1);
            packed[b * BSTRIDE + p] = ((unsigned)(vd.z & (BNODES - 1)) << 17) | (unsigned)vs.z;
            b = vd.w >> BSHIFT; p = atomicAdd(&h[b], 1);
            packed[b * BSTRIDE + p] = ((unsigned)(vd.w & (BNODES - 1)) << 17) | (unsigned)vs.w;
        } else {
            for (int k = 0; k < 4; ++k) {
                int ee = e + k;
                if (ee < E) {
                    int s = ei[ee], d = ei[E + ee];
                    int b = d >> BSHIFT;
                    int p = atomicAdd(&h[b], 1);
                    packed[b * BSTRIDE + p] = ((unsigned)(d & (BNODES - 1)) << 17) | (unsigned)s;
                }
            }
        }
    }
}

// ---------------- per-bucket deg -> dinv/u ----------------

__global__ __launch_bounds__(TPB) void k_deg_u(const unsigned* __restrict__ packed,
                                               const int* __restrict__ gcur,
                                               const float* __restrict__ x,
                                               float* __restrict__ dinv,
                                               float* __restrict__ u, int N) {
    __shared__ int cnt[8][BNODES];
    for (int k = threadIdx.x; k < 8 * BNODES; k += TPB) ((int*)cnt)[k] = 0;
    __syncthreads();
    int b = blockIdx.x;
    int sz = gcur[b];
    const unsigned* base = packed + (size_t)b * BSTRIDE;
    const uint4* base4 = (const uint4*)base;
    int wv = threadIdx.x >> 6;
    int nq4 = sz >> 2;
    int half = nq4 >> 1;
    for (int j = threadIdx.x; j < half; j += TPB) {
        uint4 p = base4[j];
        uint4 q = base4[j + half];
        atomicAdd(&cnt[wv][(p.x >> 17) & 127], 1);
        atomicAdd(&cnt[wv][(p.y >> 17) & 127], 1);
        atomicAdd(&cnt[wv][(p.z >> 17) & 127], 1);
        atomicAdd(&cnt[wv][(p.w >> 17) & 127], 1);
        atomicAdd(&cnt[wv][(q.x >> 17) & 127], 1);
        atomicAdd(&cnt[wv][(q.y >> 17) & 127], 1);
        atomicAdd(&cnt[wv][(q.z >> 17) & 127], 1);
        atomicAdd(&cnt[wv][(q.w >> 17) & 127], 1);
    }
    for (int j = half * 8 + threadIdx.x; j < sz; j += TPB) {   // tail < 12 words
        unsigned p = base[j];
        atomicAdd(&cnt[wv][(p >> 17) & 127], 1);
    }
    __syncthreads();
    if (threadIdx.x < BNODES) {
        int t = threadIdx.x;
        int node = (b << BSHIFT) + t;
        if (node < N) {
            int deg = 0;
            #pragma unroll
            for (int c = 0; c < 8; ++c) deg += cnt[c][t];
            float di = rsqrtf((float)(deg + 1));   // +1 self-loop
            dinv[node] = di;
            u[node] = di * x[node];
        }
    }
}

// ---------------- layer-1 aggregation + MLP ----------------

__global__ __launch_bounds__(TPB) void k_agg1(const unsigned* __restrict__ packed,
                                              const int* __restrict__ gcur,
                                              const float* __restrict__ dinv,
                                              const float* __restrict__ u,
                                              const float* __restrict__ W1,
                                              const float* __restrict__ b1,
                                              const float* __restrict__ W2,
                                              float2* __restrict__ w, int N) {
    __shared__ float acc[8][BNODES];
    __shared__ float sW1[64], sb1[64], sW2[128];
    if (threadIdx.x < 64) { sW1[threadIdx.x] = W1[threadIdx.x]; sb1[threadIdx.x] = b1[threadIdx.x]; }
    else if (threadIdx.x >= 64 && threadIdx.x < 192) sW2[threadIdx.x - 64] = W2[threadIdx.x - 64];
    for (int k = threadIdx.x; k < 8 * BNODES; k += TPB) ((float*)acc)[k] = 0.f;
    __syncthreads();
    int b = blockIdx.x;
    int sz = gcur[b];
    const unsigned* base = packed + (size_t)b * BSTRIDE;
    const uint4* base4 = (const uint4*)base;
    int wv = threadIdx.x >> 6;
    int nq4 = sz >> 2;
    int half = nq4 >> 1;
    for (int j = threadIdx.x; j < half; j += TPB) {
        uint4 p = base4[j];
        uint4 q = base4[j + half];
        float v0 = u[p.x & 0x1FFFF];
        float v1 = u[p.y & 0x1FFFF];
        float v2 = u[p.z & 0x1FFFF];
        float v3 = u[p.w & 0x1FFFF];
        float v4 = u[q.x & 0x1FFFF];
        float v5 = u[q.y & 0x1FFFF];
        float v6 = u[q.z & 0x1FFFF];
        float v7 = u[q.w & 0x1FFFF];
        atomicAdd(&acc[wv][(p.x >> 17) & 127], v0);
        atomicAdd(&acc[wv][(p.y >> 17) & 127], v1);
        atomicAdd(&acc[wv][(p.z >> 17) & 127], v2);
        atomicAdd(&acc[wv][(p.w >> 17) & 127], v3);
        atomicAdd(&acc[wv][(q.x >> 17) & 127], v4);
        atomicAdd(&acc[wv][(q.y >> 17) & 127], v5);
        atomicAdd(&acc[wv][(q.z >> 17) & 127], v6);
        atomicAdd(&acc[wv][(q.w >> 17) & 127], v7);
    }
    for (int j = half * 8 + threadIdx.x; j < sz; j += TPB) {
        unsigned p = base[j];
        atomicAdd(&acc[wv][(p >> 17) & 127], u[p & 0x1FFFF]);
    }
    __syncthreads();
    if (threadIdx.x < BNODES) {
        int t = threadIdx.x;
        int node = (b << BSHIFT) + t;
        if (node < N) {
            float s = 0.f;
            #pragma unroll
            for (int c = 0; c < 8; ++c) s += acc[c][t];
            float di = dinv[node];
            float sv = di * (s + u[node]);       // self-loop term dinv*u
            float z0 = 0.f, z1 = 0.f;
            #pragma unroll
            for (int j = 0; j < 64; ++j) {
                float h = fmaxf(fmaf(sv, sW1[j], sb1[j]), 0.f);
                z0 = fmaf(h, sW2[2 * j], z0);
                z1 = fmaf(h, sW2[2 * j + 1], z1);
            }
            w[node] = make_float2(di * z0, di * z1);  // pre-scaled by dinv[src]
        }
    }
}

// ---------------- layer-2 aggregation + log_softmax + mean ----------------

__global__ __launch_bounds__(TPB) void k_agg2(const unsigned* __restrict__ packed,
                                              const int* __restrict__ gcur,
                                              const float* __restrict__ dinv,
                                              const float2* __restrict__ w,
                                              const float* __restrict__ b2,
                                              float* __restrict__ accum, int N) {
    __shared__ float accx[8][BNODES], accy[8][BNODES];
    for (int k = threadIdx.x; k < 8 * BNODES; k += TPB) {
        ((float*)accx)[k] = 0.f;
        ((float*)accy)[k] = 0.f;
    }
    __syncthreads();
    int b = blockIdx.x;
    int sz = gcur[b];
    const unsigned* base = packed + (size_t)b * BSTRIDE;
    const uint4* base4 = (const uint4*)base;
    int wv = threadIdx.x >> 6;
    int nq4 = sz >> 2;
    int half = nq4 >> 1;
    for (int j = threadIdx.x; j < half; j += TPB) {
        uint4 p = base4[j];
        uint4 q = base4[j + half];
        float2 v0 = w[p.x & 0x1FFFF];
        float2 v1 = w[p.y & 0x1FFFF];
        float2 v2 = w[p.z & 0x1FFFF];
        float2 v3 = w[p.w & 0x1FFFF];
        float2 v4 = w[q.x & 0x1FFFF];
        float2 v5 = w[q.y & 0x1FFFF];
        float2 v6 = w[q.z & 0x1FFFF];
        float2 v7 = w[q.w & 0x1FFFF];
        int l0 = (p.x >> 17) & 127, l1 = (p.y >> 17) & 127;
        int l2 = (p.z >> 17) & 127, l3 = (p.w >> 17) & 127;
        int l4 = (q.x >> 17) & 127, l5 = (q.y >> 17) & 127;
        int l6 = (q.z >> 17) & 127, l7 = (q.w >> 17) & 127;
        atomicAdd(&accx[wv][l0], v0.x); atomicAdd(&accy[wv][l0], v0.y);
        atomicAdd(&accx[wv][l1], v1.x); atomicAdd(&accy[wv][l1], v1.y);
        atomicAdd(&accx[wv][l2], v2.x); atomicAdd(&accy[wv][l2], v2.y);
        atomicAdd(&accx[wv][l3], v3.x); atomicAdd(&accy[wv][l3], v3.y);
        atomicAdd(&accx[wv][l4], v4.x); atomicAdd(&accy[wv][l4], v4.y);
        atomicAdd(&accx[wv][l5], v5.x); atomicAdd(&accy[wv][l5], v5.y);
        atomicAdd(&accx[wv][l6], v6.x); atomicAdd(&accy[wv][l6], v6.y);
        atomicAdd(&accx[wv][l7], v7.x); atomicAdd(&accy[wv][l7], v7.y);
    }
    for (int j = half * 8 + threadIdx.x; j < sz; j += TPB) {
        unsigned p = base[j];
        float2 v = w[p & 0x1FFFF];
        int l = (p >> 17) & 127;
        atomicAdd(&accx[wv][l], v.x);
        atomicAdd(&accy[wv][l], v.y);
    }
    __syncthreads();
    float l0 = 0.f, l1 = 0.f;
    if (threadIdx.x < BNODES) {
        int t = threadIdx.x;
        int node = (b << BSHIFT) + t;
        if (node < N) {
            float sx = 0.f, sy = 0.f;
            #pragma unroll
            for (int c = 0; c < 8; ++c) { sx += accx[c][t]; sy += accy[c][t]; }
            float di = dinv[node];
            float2 wi = w[node];
            float a0 = di * (sx + wi.x) + b2[0];
            float a1 = di * (sy + wi.y) + b2[1];
            float m = fmaxf(a0, a1);
            float lse = m + logf(expf(a0 - m) + expf(a1 - m));
            l0 = a0 - lse;
            l1 = a1 - lse;
        }
    }
    #pragma unroll
    for (int off = 32; off > 0; off >>= 1) {
        l0 += __shfl_down(l0, off, 64);
        l1 += __shfl_down(l1, off, 64);
    }
    __shared__ float s0[TPB / 64], s1[TPB / 64];
    int wid = threadIdx.x >> 6, lane = threadIdx.x & 63;
    if (lane == 0) { s0[wid] = l0; s1[wid] = l1; }
    __syncthreads();
    if (threadIdx.x == 0) {
        float t0 = 0.f, t1 = 0.f;
        #pragma unroll
        for (int k = 0; k < TPB / 64; ++k) { t0 += s0[k]; t1 += s1[k]; }
        atomicAdd(&accum[0], t0);
        atomicAdd(&accum[1], t1);
    }
}

__global__ void k_finalize(const float* __restrict__ accum, float* __restrict__ out, float invN) {
    out[0] = accum[0] * invN;
    out[1] = accum[1] * invN;
}

// ---------------- fallback (global-atomic path) ----------------

#define FTPB 256
__global__ void k_hist(const int* __restrict__ dst, int E, int* __restrict__ deg) {
    int e = blockIdx.x * FTPB + threadIdx.x;
    if (e < E) atomicAdd(&deg[dst[e]], 1);
}
__global__ void k_dinv_u(const int* __restrict__ deg, const float* __restrict__ x,
                         float* __restrict__ dinv, float* __restrict__ u, int N) {
    int i = blockIdx.x * FTPB + threadIdx.x;
    if (i < N) {
        float di = rsqrtf((float)(deg[i] + 1));
        dinv[i] = di;
        u[i] = di * x[i];
    }
}
__global__ void k_scatter1(const int* __restrict__ ei, int E,
                           const float* __restrict__ u, float* __restrict__ t) {
    int e = blockIdx.x * FTPB + threadIdx.x;
    if (e < E) atomicAdd(&t[ei[E + e]], u[ei[e]]);
}
__global__ void k_node_mid_fb(const float* __restrict__ dinv, const float* __restrict__ u,
                              const float* __restrict__ t,
                              const float* __restrict__ W1, const float* __restrict__ b1,
                              const float* __restrict__ W2, float2* __restrict__ w, int N) {
    __shared__ float sW1[64], sb1[64], sW2[128];
    if (threadIdx.x < 64) { sW1[threadIdx.x] = W1[threadIdx.x]; sb1[threadIdx.x] = b1[threadIdx.x]; }
    if (threadIdx.x < 128) sW2[threadIdx.x] = W2[threadIdx.x];
    __syncthreads();
    int i = blockIdx.x * FTPB + threadIdx.x;
    if (i < N) {
        float di = dinv[i];
        float s = di * (t[i] + u[i]);
        float z0 = 0.f, z1 = 0.f;
        #pragma unroll
        for (int j = 0; j < 64; ++j) {
            float h = fmaxf(fmaf(s, sW1[j], sb1[j]), 0.f);
            z0 = fmaf(h, sW2[2 * j], z0);
            z1 = fmaf(h, sW2[2 * j + 1], z1);
        }
        w[i] = make_float2(di * z0, di * z1);
    }
}
__global__ void k_scatter2(const int* __restrict__ ei, int E,
                           const float2* __restrict__ w, float* __restrict__ acc) {
    int e = blockIdx.x * FTPB + threadIdx.x;
    if (e < E) {
        float2 ws = w[ei[e]];
        int d = ei[E + e];
        atomicAdd(&acc[2 * d], ws.x);
        atomicAdd(&acc[2 * d + 1], ws.y);
    }
}
__global__ void k_node_out_fb(const float* __restrict__ dinv, const float2* __restrict__ w,
                              const float2* __restrict__ acc, const float* __restrict__ b2,
                              float* __restrict__ accum, int N) {
    int i = blockIdx.x * FTPB + threadIdx.x;
    float l0 = 0.f, l1 = 0.f;
    if (i < N) {
        float di = dinv[i];
        float2 a = acc[i];
        float2 ww = w[i];
        float a0 = di * (a.x + ww.x) + b2[0];
        float a1 = di * (a.y + ww.y) + b2[1];
        float m = fmaxf(a0, a1);
        float lse = m + logf(expf(a0 - m) + expf(a1 - m));
        l0 = a0 - lse;
        l1 = a1 - lse;
    }
    #pragma unroll
    for (int off = 32; off > 0; off >>= 1) {
        l0 += __shfl_down(l0, off, 64);
        l1 += __shfl_down(l1, off, 64);
    }
    __shared__ float s0[FTPB / 64], s1[FTPB / 64];
    int wid = threadIdx.x >> 6, lane = threadIdx.x & 63;
    if (lane == 0) { s0[wid] = l0; s1[wid] = l1; }
    __syncthreads();
    if (threadIdx.x == 0) {
        float t0 = 0.f, t1 = 0.f;
        #pragma unroll
        for (int k = 0; k < FTPB / 64; ++k) { t0 += s0[k]; t1 += s1[k]; }
        atomicAdd(&accum[0], t0);
        atomicAdd(&accum[1], t1);
    }
}

extern "C" void kernel_launch(void* const* d_in, const int* in_sizes, int n_in,
                              void* d_out, int out_size, void* d_ws, size_t ws_size,
                              hipStream_t stream) {
    const float* x  = (const float*)d_in[0];
    const int*   ei = (const int*)d_in[1];
    const float* W1 = (const float*)d_in[2];
    const float* b1 = (const float*)d_in[3];
    const float* W2 = (const float*)d_in[4];
    const float* b2 = (const float*)d_in[5];
    float* out = (float*)d_out;

    const int N = in_sizes[0];
    const int E = in_sizes[1] / 2;
    const int nbuck = (N + BNODES - 1) >> BSHIFT;
    const int gridN = (N + FTPB - 1) / FTPB;
    const int gridE = (E + FTPB - 1) / FTPB;

    size_t offPacked = 0;
    size_t offW      = offPacked + (size_t)nbuck * BSTRIDE * 4;
    size_t offDinv   = offW + (size_t)N * 8;
    size_t offU      = offDinv + (size_t)N * 4;
    size_t offGcur   = offU + (size_t)N * 4;
    size_t offAccum  = offGcur + (size_t)nbuck * 4;
    size_t need      = offAccum + 8;

    if (ws_size >= need && nbuck <= MAXBUCK && N <= (1 << 17)) {
        unsigned* packed = (unsigned*)((char*)d_ws + offPacked);
        float2*   w      = (float2*)((char*)d_ws + offW);
        float*    dinv   = (float*)((char*)d_ws + offDinv);
        float*    u      = (float*)((char*)d_ws + offU);
        int*      gcur   = (int*)((char*)d_ws + offGcur);
        float*    accum  = (float*)((char*)d_ws + offAccum);

        hipMemsetAsync(gcur, 0, (size_t)nbuck * 4 + 8, stream);

        int epb = (((E + SORT_BLK - 1) / SORT_BLK) + 3) & ~3;

        k_sort<<<SORT_BLK, TPB, 0, stream>>>(ei, E, epb, nbuck, gcur, packed);
        k_deg_u<<<nbuck, TPB, 0, stream>>>(packed, gcur, x, dinv, u, N);
        k_agg1<<<nbuck, TPB, 0, stream>>>(packed, gcur, dinv, u, W1, b1, W2, w, N);
        k_agg2<<<nbuck, TPB, 0, stream>>>(packed, gcur, dinv, (const float2*)w, b2, accum, N);
        k_finalize<<<1, 64, 0, stream>>>(accum, out, 1.0f / (float)N);
    } else {
        int*   deg   = (int*)d_ws;
        float* t     = (float*)(deg + N);
        float* acc   = t + N;
        float* accum = acc + 2 * N;
        float* dinv  = accum + 2;
        float* u     = dinv + N;
        float2* w    = (float2*)(u + N);
        hipMemsetAsync(d_ws, 0, (size_t)(4 * N + 2) * sizeof(float), stream);
        k_hist<<<gridE, FTPB, 0, stream>>>(ei + E, E, deg);
        k_dinv_u<<<gridN, FTPB, 0, stream>>>(deg, x, dinv, u, N);
        k_scatter1<<<gridE, FTPB, 0, stream>>>(ei, E, u, t);
        k_node_mid_fb<<<gridN, FTPB, 0, stream>>>(dinv, u, t, W1, b1, W2, w, N);
        k_scatter2<<<gridE, FTPB, 0, stream>>>(ei, E, w, acc);
        k_node_out_fb<<<gridN, FTPB, 0, stream>>>(dinv, w, (const float2*)acc, b2, accum, N);
        k_finalize<<<1, 64, 0, stream>>>(accum, out, 1.0f / (float)N);
    }
}